// Round 7
// baseline (378.526 us; speedup 1.0000x reference)
//
#include <hip/hip_runtime.h>
#include <cmath>

#define DM 512
#define DS 256
#define NL 4
#define BATCH 8
#define SEQ 2048
#define MROWS (BATCH*SEQ)   // 16384
#define LCH 32
#define NCH 64              // LCH*NCH == SEQ

typedef unsigned short ushort_t;
typedef unsigned int uint_t;
typedef __attribute__((ext_vector_type(8))) short short8;
typedef __attribute__((ext_vector_type(4))) float floatx4;

__device__ __forceinline__ float sigmoidf_(float v) { return 1.0f / (1.0f + __expf(-v)); }

__device__ __forceinline__ ushort_t f2bf(float f) {
    union { float f; unsigned int u; } c; c.f = f;
    unsigned int u = c.u;
    u += 0x7fffu + ((u >> 16) & 1u);          // RNE
    return (ushort_t)(u >> 16);
}
__device__ __forceinline__ float bf2f(uint_t h) {
    union { unsigned int u; float f; } c; c.u = (h & 0xffffu) << 16; return c.f;
}
__device__ __forceinline__ uint_t pack2(float a, float b) {
    return (uint_t)f2bf(a) | ((uint_t)f2bf(b) << 16);
}

#define AS1 __attribute__((address_space(1)))
#define AS3 __attribute__((address_space(3)))
__device__ __forceinline__ void gl_lds16(const void* g, void* l) {
    __builtin_amdgcn_global_load_lds((const AS1 uint_t*)g, (AS3 uint_t*)l, 16, 0, 0);
}

// All GEMM arguments in one struct: no positional-arity pitfalls.
struct GemmArgs {
    const ushort_t* A;       // [M,K] bf16
    const ushort_t* Wa;      // [N,K] bf16
    const ushort_t* Wb;      // [N,K] bf16 (DUAL only)
    const ushort_t* xbf_in;  // EPI2/EPI3: bf16 x
    const float* gam;        // EPI1
    const float* Dv;         // EPI2
    float* of32;             // EPI4
    ushort_t* obf;           // EPI0..3
    const float* resp;       // EPI3
    const float* lamre;      // EPI1: lambda tables for fused chunk-end scan
    const float* lamim;      // EPI1
    float* carry;            // EPI1: [B*NCH,512] chunk-end output
    int K;
    int N;
    int layer;
};

// ---------------------------------------------------------------------------
// R6 post-mortem: 8-wave/512t split REVERTED — per-wave MFMA density fell
// (ds_read:MFMA 0.5 -> 0.75) and 8-wave barriers cost more than the extra
// occupancy bought (+10us). R7 = R5 structure (4-wave/256t, 2x2 wave grid,
// 16 MFMA/wave/K-iter) + BK=64 for SINGLE GEMMs (sgemm64 below): halves the
// per-K-iter barrier+vmcnt(0)-drain count. Dual keeps BK=32 (BK=64 would be
// 96KB LDS -> 1 block/CU).
//
// mgemm (BK=32): EPI 3 (GLU dual) and 4 (decoder BN=64) only.
// R3 post-mortem: XCD swizzle stays REVERTED (L3-resident regime).
// ---------------------------------------------------------------------------
#define PREFETCH_TILE(it_, buf_)                                                        \
    do {                                                                                \
        const size_t kb_ = (size_t)(it_) * 64;                                          \
        char* dst_ = smem + (buf_) * HALF;                                              \
        gl_lds16(Ap + (size_t)(wid * 16 + lrow) * Kb + kb_, dst_ + wid * 1024);         \
        gl_lds16(Ap + (size_t)((wid + 4) * 16 + lrow) * Kb + kb_,                       \
                 dst_ + (wid + 4) * 1024);                                              \
        gl_lds16(B0p + (size_t)(wid * 16 + lrow) * Kb + kb_, dst_ + AB + wid * 1024);   \
        if constexpr (BN == 128) {                                                      \
            gl_lds16(B0p + (size_t)((wid + 4) * 16 + lrow) * Kb + kb_,                  \
                     dst_ + AB + (wid + 4) * 1024);                                     \
        }                                                                               \
        if constexpr (DUAL) {                                                           \
            gl_lds16(B1p + (size_t)(wid * 16 + lrow) * Kb + kb_,                        \
                     dst_ + AB + BB + wid * 1024);                                      \
            if constexpr (BN == 128) {                                                  \
                gl_lds16(B1p + (size_t)((wid + 4) * 16 + lrow) * Kb + kb_,              \
                         dst_ + AB + BB + (wid + 4) * 1024);                            \
            }                                                                           \
        }                                                                               \
    } while (0)

template<int BN, int EPI, int DUAL>
__launch_bounds__(256, DUAL ? 2 : 3)
__global__ void mgemm(const GemmArgs p) {
    constexpr int BM = 128;
    constexpr int MT = (BN == 128) ? 4 : 2;
    constexpr int NT = 4;
    constexpr int WROWS = MT * 16;
    constexpr int AB = 8192;                         // A stage bytes (128 x 64B)
    constexpr int BB = (BN == 128) ? 8192 : 4096;
    constexpr int B1B = DUAL ? BB : 0;
    constexpr int HALF = AB + BB + B1B;              // one pipeline stage
    constexpr int EPB = (EPI == 4) ? 0 : 64 * 132 * 4;
    constexpr int SMB = (2 * HALF > EPB) ? 2 * HALF : EPB;
    __shared__ __align__(16) char smem[SMB];

    const int K = p.K, N = p.N;
    const int tid = threadIdx.x, lane = tid & 63, wid = tid >> 6;
    const int wm = (BN == 128) ? (wid & 1) : wid;
    const int wn = (BN == 128) ? (wid >> 1) : 0;
    const int m0 = blockIdx.x * BM, n0 = blockIdx.y * BN;
    const int q = lane >> 4, r16 = lane & 15;
    const int lrow = lane >> 2;
    const size_t Kb = (size_t)K * 2;                 // row bytes
    const char* Ap  = (const char*)p.A  + (size_t)m0 * Kb + (lane & 3) * 16;
    const char* B0p = (const char*)p.Wa + (size_t)n0 * Kb + (lane & 3) * 16;
    const char* B1p = (const char*)p.Wb + (size_t)n0 * Kb + (lane & 3) * 16;

    floatx4 acc0[MT][NT] = {};
    floatx4 acc1[DUAL ? MT : 1][DUAL ? NT : 1] = {};

    const int iters = K >> 5;
    PREFETCH_TILE(0, 0);
    for (int it = 0; it < iters; ++it) {
        __syncthreads();
        if (it + 1 < iters) PREFETCH_TILE(it + 1, (it + 1) & 1);
        const ushort_t* As  = (const ushort_t*)(smem + (it & 1) * HALF);
        const ushort_t* Bs0 = (const ushort_t*)(smem + (it & 1) * HALF + AB);
        const ushort_t* Bs1 = (const ushort_t*)(smem + (it & 1) * HALF + AB + BB);

        short8 af[MT], b0[NT], b1[DUAL ? NT : 1];
#pragma unroll
        for (int i = 0; i < MT; ++i)
            af[i] = *(const short8*)&As[(wm * WROWS + i * 16 + r16) * 32 + q * 8];
#pragma unroll
        for (int j = 0; j < NT; ++j) {
            b0[j] = *(const short8*)&Bs0[(wn * 64 + j * 16 + r16) * 32 + q * 8];
            if constexpr (DUAL)
                b1[j] = *(const short8*)&Bs1[(wn * 64 + j * 16 + r16) * 32 + q * 8];
        }
#pragma unroll
        for (int i = 0; i < MT; ++i)
#pragma unroll
            for (int j = 0; j < NT; ++j) {
                acc0[i][j] = __builtin_amdgcn_mfma_f32_16x16x32_bf16(af[i], b0[j], acc0[i][j], 0, 0, 0);
                if constexpr (DUAL)
                    acc1[i][j] = __builtin_amdgcn_mfma_f32_16x16x32_bf16(af[i], b1[j], acc1[i][j], 0, 0, 0);
            }
    }

    if constexpr (EPI == 4) {
#pragma unroll
        for (int i = 0; i < MT; ++i)
#pragma unroll
            for (int j = 0; j < NT; ++j)
#pragma unroll
                for (int rr = 0; rr < 4; ++rr) {
                    const int row = m0 + wm * WROWS + i * 16 + q * 4 + rr;
                    const int col = wn * 64 + j * 16 + r16;
                    p.of32[(size_t)row * N + col] = acc0[i][j][rr];
                }
        return;
    } else {
        float* eps = (float*)smem;                    // [64][132]
        float rsv = 0.f;
        if constexpr (EPI == 3) rsv = sigmoidf_(p.resp[p.layer]);
        constexpr int ERND = 2;                       // acc i-slabs per eps round

#pragma unroll
        for (int i = 0; i < MT; i += ERND) {
            __syncthreads();
#pragma unroll
            for (int ii = 0; ii < ERND; ++ii) {
#pragma unroll
                for (int j = 0; j < NT; ++j) {
                    const int colt = wn * 64 + j * 16 + r16;
#pragma unroll
                    for (int rr = 0; rr < 4; ++rr) {
                        float v = acc0[i + ii][j][rr];
                        if constexpr (EPI == 3) v = rsv * v * sigmoidf_(acc1[i + ii][j][rr]);
                        eps[(ii * 32 + wm * 16 + q * 4 + rr) * 132 + colt] = v;
                    }
                }
            }
            __syncthreads();
            const int row_r = tid >> 3, colg = (tid & 7) * 16;
#pragma unroll
            for (int ii = 0; ii < ERND; ++ii) {
                const int lr = (row_r >> 4) * 64 + (i + ii) * 16 + (row_r & 15);
                const int grow = m0 + lr;
                const int gcol = n0 + colg;
                float4 f[4];
#pragma unroll
                for (int c = 0; c < 4; ++c)
                    f[c] = *(float4*)&eps[(ii * 32 + row_r) * 132 + colg + c * 4];
                const size_t ob = (size_t)grow * N + gcol;

                if constexpr (EPI == 3) {
                    uint_t xp[8];
                    *(uint4*)(xp)     = *(const uint4*)(p.xbf_in + ob);
                    *(uint4*)(xp + 4) = *(const uint4*)(p.xbf_in + ob + 8);
#pragma unroll
                    for (int c = 0; c < 4; ++c) {
                        f[c].x += bf2f(xp[2 * c]);
                        f[c].y += bf2f(xp[2 * c] >> 16);
                        f[c].z += bf2f(xp[2 * c + 1]);
                        f[c].w += bf2f(xp[2 * c + 1] >> 16);
                    }
                }
                uint4 p0, p1;
                p0.x = pack2(f[0].x, f[0].y); p0.y = pack2(f[0].z, f[0].w);
                p0.z = pack2(f[1].x, f[1].y); p0.w = pack2(f[1].z, f[1].w);
                p1.x = pack2(f[2].x, f[2].y); p1.y = pack2(f[2].z, f[2].w);
                p1.z = pack2(f[3].x, f[3].y); p1.w = pack2(f[3].z, f[3].w);
                *(uint4*)(p.obf + ob) = p0;
                *(uint4*)(p.obf + ob + 8) = p1;
            }
        }
    }
}

// ---------------------------------------------------------------------------
// Single-B GEMM, BK=64: two R5-style 8KB sub-tiles per stage (64B rows,
// proven conflict-free layout; sub-tile ks at byte offset ks*8192, read with
// element base ks*4096). Halves the barrier/vmcnt(0)-drain count vs BK=32
// (K=512: 8 windows instead of 16). LDS 2x32KB=64KB -> 2 blocks/CU, which
// the 512-block grid already capped -> no occupancy loss (avoids m132's
// BK=128 failure mode).
// EPI: 0 encoder / 1 Bu (+fused chunk-end scan via zst stash) / 2 z.
// ---------------------------------------------------------------------------
template<int EPI>
__launch_bounds__(256, 3)
__global__ void sgemm64(const GemmArgs p) {
    constexpr int BM = 128;
    constexpr int MT = 4, NT = 4;
    constexpr int AB = 16384;                        // A stage: 2 x [128][64B]
    constexpr int BB = 16384;
    constexpr int HALF = AB + BB;                    // 32K
    constexpr int EPB = (EPI == 1) ? (32 * 132 * 4 + 128 * 66 * 4) : 64 * 132 * 4;
    constexpr int SMB = (2 * HALF > EPB) ? 2 * HALF : EPB;   // 64K
    __shared__ __align__(16) char smem[SMB];

    const int K = p.K, N = p.N;
    const int tid = threadIdx.x, lane = tid & 63, wid = tid >> 6;
    const int wm = wid & 1, wn = wid >> 1;           // 2x2 wave grid, 64x64/wave
    const int m0 = blockIdx.x * BM, n0 = blockIdx.y * 128;
    const int q = lane >> 4, r16 = lane & 15;
    const int lrow = lane >> 2;
    const size_t Kb = (size_t)K * 2;                 // row bytes
    const char* Ap  = (const char*)p.A  + (size_t)m0 * Kb + (lane & 3) * 16;
    const char* B0p = (const char*)p.Wa + (size_t)n0 * Kb + (lane & 3) * 16;

    floatx4 acc0[MT][NT] = {};

#define PFS(it_, buf_)                                                                      \
    do {                                                                                    \
        const size_t kb0_ = (size_t)(it_) * 128;                                            \
        {   /* ks = 0 */                                                                    \
            const size_t kb_ = kb0_;                                                        \
            char* dst_ = smem + (buf_) * HALF;                                              \
            gl_lds16(Ap + (size_t)(wid * 16 + lrow) * Kb + kb_, dst_ + wid * 1024);         \
            gl_lds16(Ap + (size_t)((wid + 4) * 16 + lrow) * Kb + kb_,                       \
                     dst_ + (wid + 4) * 1024);                                              \
            gl_lds16(B0p + (size_t)(wid * 16 + lrow) * Kb + kb_, dst_ + AB + wid * 1024);   \
            gl_lds16(B0p + (size_t)((wid + 4) * 16 + lrow) * Kb + kb_,                      \
                     dst_ + AB + (wid + 4) * 1024);                                         \
        }                                                                                   \
        {   /* ks = 1 */                                                                    \
            const size_t kb_ = kb0_ + 64;                                                   \
            char* dst_ = smem + (buf_) * HALF + 8192;                                       \
            gl_lds16(Ap + (size_t)(wid * 16 + lrow) * Kb + kb_, dst_ + wid * 1024);         \
            gl_lds16(Ap + (size_t)((wid + 4) * 16 + lrow) * Kb + kb_,                       \
                     dst_ + (wid + 4) * 1024);                                              \
            gl_lds16(B0p + (size_t)(wid * 16 + lrow) * Kb + kb_, dst_ + AB + wid * 1024);   \
            gl_lds16(B0p + (size_t)((wid + 4) * 16 + lrow) * Kb + kb_,                      \
                     dst_ + AB + (wid + 4) * 1024);                                         \
        }                                                                                   \
    } while (0)

    const int iters = K >> 6;                        // 64-k windows
    PFS(0, 0);
    for (int it = 0; it < iters; ++it) {
        __syncthreads();
        if (it + 1 < iters) PFS(it + 1, (it + 1) & 1);
        const ushort_t* As  = (const ushort_t*)(smem + (it & 1) * HALF);
        const ushort_t* Bs0 = (const ushort_t*)(smem + (it & 1) * HALF + AB);

#pragma unroll
        for (int ks = 0; ks < 2; ++ks) {
            short8 af[MT], b0[NT];
#pragma unroll
            for (int i = 0; i < MT; ++i)
                af[i] = *(const short8*)&As[ks * 4096 + (wm * 64 + i * 16 + r16) * 32 + q * 8];
#pragma unroll
            for (int j = 0; j < NT; ++j)
                b0[j] = *(const short8*)&Bs0[ks * 4096 + (wn * 64 + j * 16 + r16) * 32 + q * 8];
#pragma unroll
            for (int i = 0; i < MT; ++i)
#pragma unroll
                for (int j = 0; j < NT; ++j)
                    acc0[i][j] = __builtin_amdgcn_mfma_f32_16x16x32_bf16(af[i], b0[j], acc0[i][j], 0, 0, 0);
        }
    }
#undef PFS

    // ---- epilogue (R5-verified): LDS transpose + bf16 pack ----
    float* eps = (float*)smem;                       // [ERND*32][132]
    uint_t* zst = (uint_t*)(smem + 32 * 132 * 4);    // EPI1 only: [128][66]
    constexpr int ERND = (EPI == 1) ? 1 : 2;

#pragma unroll
    for (int i = 0; i < MT; i += ERND) {
        __syncthreads();
#pragma unroll
        for (int ii = 0; ii < ERND; ++ii) {
#pragma unroll
            for (int j = 0; j < NT; ++j) {
                const int colt = wn * 64 + j * 16 + r16;
#pragma unroll
                for (int rr = 0; rr < 4; ++rr) {
                    float v = acc0[i + ii][j][rr];
                    if constexpr (EPI == 1) v *= p.gam[(n0 + colt) >> 1];
                    eps[(ii * 32 + wm * 16 + q * 4 + rr) * 132 + colt] = v;
                }
            }
        }
        __syncthreads();
        const int row_r = tid >> 3, colg = (tid & 7) * 16;
#pragma unroll
        for (int ii = 0; ii < ERND; ++ii) {
            const int lr = (row_r >> 4) * 64 + (i + ii) * 16 + (row_r & 15);
            const int grow = m0 + lr;
            const int gcol = n0 + colg;
            float4 f[4];
#pragma unroll
            for (int c = 0; c < 4; ++c)
                f[c] = *(float4*)&eps[(ii * 32 + row_r) * 132 + colg + c * 4];
            const size_t ob = (size_t)grow * N + gcol;

            if constexpr (EPI == 2) {
                uint_t xp[8];
                *(uint4*)(xp)     = *(const uint4*)(p.xbf_in + ob);
                *(uint4*)(xp + 4) = *(const uint4*)(p.xbf_in + ob + 8);
#pragma unroll
                for (int c = 0; c < 4; ++c) {
                    float4 dv = *(const float4*)(p.Dv + gcol + c * 4);
                    f[c].x += dv.x * bf2f(xp[2 * c]);
                    f[c].y += dv.y * bf2f(xp[2 * c] >> 16);
                    f[c].z += dv.z * bf2f(xp[2 * c + 1]);
                    f[c].w += dv.w * bf2f(xp[2 * c + 1] >> 16);
                }
            }
            uint4 p0, p1;
            p0.x = pack2(f[0].x, f[0].y); p0.y = pack2(f[0].z, f[0].w);
            p0.z = pack2(f[1].x, f[1].y); p0.w = pack2(f[1].z, f[1].w);
            p1.x = pack2(f[2].x, f[2].y); p1.y = pack2(f[2].z, f[2].w);
            p1.z = pack2(f[3].x, f[3].y); p1.w = pack2(f[3].z, f[3].w);
            *(uint4*)(p.obf + ob) = p0;
            *(uint4*)(p.obf + ob + 8) = p1;
            if constexpr (EPI == 1) {
                const int c0 = colg >> 1;
                *(uint4*)&zst[lr * 66 + c0]     = p0;
                *(uint4*)&zst[lr * 66 + c0 + 4] = p1;
            }
        }
    }

    if constexpr (EPI == 1) {
        // fused chunk-end scan: thread t -> chunk c4 (of 4), local state s6
        __syncthreads();
        const int c4 = tid >> 6, s6 = tid & 63;
        const int sg = (n0 >> 1) + s6;                 // global state
        const float lr_ = p.lamre[sg], li_ = p.lamim[sg];
        float hr = 0.f, hi = 0.f;
#pragma unroll 8
        for (int i2 = 0; i2 < LCH; ++i2) {
            uint_t uu = zst[(c4 * LCH + i2) * 66 + s6];
            float br = bf2f(uu), bi = bf2f(uu >> 16);
            float nr = fmaf(lr_, hr, fmaf(-li_, hi, br));
            float ni = fmaf(lr_, hi, fmaf(li_, hr, bi));
            hr = nr; hi = ni;
        }
        const int b = m0 >> 11;                        // m0 / SEQ
        const int cblk = ((m0 & (SEQ - 1)) >> 5) + c4; // chunk index in seq
        const size_t cb = (size_t)(b * NCH + cblk) * 512 + sg;
        p.carry[cb] = hr; p.carry[cb + DS] = hi;
    }
}

// ---------------------------------------------------------------------------
// Single prep kernel: all weight bf16 packing + u cast + lambda/gamma tables.
// ---------------------------------------------------------------------------
__global__ void prep_all(const float* __restrict__ u, const float* __restrict__ enc,
                         const float* __restrict__ dec, const float* __restrict__ nu,
                         const float* __restrict__ th,
                         const float* __restrict__ Bre, const float* __restrict__ Bim,
                         const float* __restrict__ Cre, const float* __restrict__ Cim,
                         const float* __restrict__ W1, const float* __restrict__ W2,
                         ushort_t* __restrict__ WBb, ushort_t* __restrict__ Wzb,
                         ushort_t* __restrict__ W1b, ushort_t* __restrict__ W2b,
                         ushort_t* __restrict__ encb, ushort_t* __restrict__ decb,
                         ushort_t* __restrict__ ubf,
                         float* __restrict__ lre, float* __restrict__ lim,
                         float* __restrict__ gm) {
    const int idx = blockIdx.x * 256 + threadIdx.x;   // 0..1M-1
    const int k = idx & 511, n = (idx >> 9) & 511, l = idx >> 18;
    {
        const int s = n >> 1, part = n & 1;
        const float* src = part ? Bim : Bre;
        WBb[idx] = f2bf(src[((size_t)l * DS + s) * DM + k]);
    }
    {
        const int s = k >> 1, part = k & 1;
        float v = part ? -Cim[((size_t)l * DM + n) * DS + s]
                       :  Cre[((size_t)l * DM + n) * DS + s];
        Wzb[idx] = f2bf(v);
    }
    W1b[idx] = f2bf(W1[idx]);
    W2b[idx] = f2bf(W2[idx]);
    ubf[idx] = f2bf(u[idx]);
    if (idx < DM * 64) { encb[idx] = f2bf(enc[idx]); decb[idx] = f2bf(dec[idx]); }
    if (idx < NL * DS) {
        float a = expf(-expf(nu[idx])), t = expf(th[idx]);
        lre[idx] = a * cosf(t);
        lim[idx] = a * sinf(t);
        gm[idx] = sqrtf(fmaxf(0.f, 1.f - a * a));
    }
}

// ---------------------------------------------------------------------------
// Lookback apply — NO inter-block waiting (R2 post-mortem: agent-scope spin
// cost ~100us). Chunk-end carries are produced by the Bu-GEMM epilogue
// (fused scan_ends). This kernel rebuilds prefix g from a depth-12 truncated
// lookback over carry (|lam^32| <= 0.194 -> 0.194^12 ~ 3e-9 truncation, far
// below bf16 noise; arithmetic verified R1-R6), then applies + writes h.
// Deterministic, no atomics, no fences.
// ---------------------------------------------------------------------------
__global__ __launch_bounds__(256) void scan_apply_lb(
        const uint_t* __restrict__ Bu, const float* __restrict__ lre_,
        const float* __restrict__ lim_, const float* __restrict__ carry,
        uint_t* __restrict__ h) {
    const int s = threadIdx.x;
    const int blk = blockIdx.x, b = blk >> 6, c = blk & 63;
    const float lre = lre_[s], lim = lim_[s];

    // lookback: g = state at end of chunk c-1 (truncated geometric sum)
    float gre = 0.f, gim = 0.f;
    if (c > 0) {
        float are = lre, aim = lim;          // lam^32 (5 squarings)
#pragma unroll
        for (int t = 0; t < 5; ++t) {
            float nr = are * are - aim * aim, ni = 2.f * are * aim;
            are = nr; aim = ni;
        }
        const int depth = (c < 12) ? c : 12;
        float pwr = 1.f, pwi = 0.f;
        for (int j = c - 1; j >= c - depth; --j) {
            const size_t jb = (size_t)(b * NCH + j) * 512 + s;
            float er = carry[jb], ei = carry[jb + DS];
            gre = fmaf(pwr, er, fmaf(-pwi, ei, gre));
            gim = fmaf(pwr, ei, fmaf(pwi, er, gim));
            float nr = pwr * are - pwi * aim, ni = pwr * aim + pwi * are;
            pwr = nr; pwi = ni;
        }
    }

    // apply: rerun recurrence from g, write h
    float hr = gre, hi = gim;
    size_t base = ((size_t)b * SEQ + (size_t)c * LCH) * DS + s;
#pragma unroll 8
    for (int i = 0; i < LCH; ++i, base += DS) {
        uint_t uu = Bu[base];
        float br = bf2f(uu), bi = bf2f(uu >> 16);
        float nr = fmaf(lre, hr, fmaf(-lim, hi, br));
        float ni = fmaf(lre, hi, fmaf(lim, hr, bi));
        hr = nr; hi = ni;
        h[base] = pack2(hr, hi);
    }
}

// ---------------------------------------------------------------------------
extern "C" void kernel_launch(void* const* d_in, const int* in_sizes, int n_in,
                              void* d_out, int out_size, void* d_ws, size_t ws_size,
                              hipStream_t stream) {
    const float* u   = (const float*)d_in[0];
    const float* enc = (const float*)d_in[1];
    const float* dec = (const float*)d_in[2];
    const float* nu  = (const float*)d_in[3];
    const float* th  = (const float*)d_in[4];
    const float* Bre = (const float*)d_in[5];
    const float* Bim = (const float*)d_in[6];
    const float* Cre = (const float*)d_in[7];
    const float* Cim = (const float*)d_in[8];
    const float* Dp  = (const float*)d_in[9];
    const float* W1  = (const float*)d_in[10];
    const float* W2  = (const float*)d_in[11];
    const float* res = (const float*)d_in[12];
    float* out = (float*)d_out;

    const size_t MD = (size_t)MROWS * DM;
    float* carry = (float*)d_ws;                         // [8*64,512] fp32
    float* lre  = carry + (size_t)BATCH * NCH * 512;
    float* lim  = lre + NL * DS;
    float* gmt  = lim + NL * DS;
    ushort_t* xbf  = (ushort_t*)(gmt + NL * DS);         // bf16 [16384,512] each:
    ushort_t* Bubf = xbf + MD;
    ushort_t* hbf  = Bubf + MD;
    ushort_t* zbf  = hbf + MD;
    ushort_t* ubf  = zbf;                                // alias: z written after u consumed
    ushort_t* WBb  = zbf + MD;                           // weights, 4x512x512 bf16 each:
    ushort_t* Wzb  = WBb + (size_t)NL * DM * DM;
    ushort_t* W1b  = Wzb + (size_t)NL * DM * DM;
    ushort_t* W2b  = W1b + (size_t)NL * DM * DM;
    ushort_t* encb = W2b + (size_t)NL * DM * DM;         // 512x64
    ushort_t* decb = encb + DM * 64;                     // 64x512

    prep_all<<<NL * DM * DM / 256, 256, 0, stream>>>(
        u, enc, dec, nu, th, Bre, Bim, Cre, Cim, W1, W2,
        WBb, Wzb, W1b, W2b, encb, decb, ubf, lre, lim, gmt);

    const dim3 gFull(MROWS / 128, DM / 128);

    // encoder: xbf = bf16(u @ enc^T)   (K=64 -> single 64-k window)
    {
        GemmArgs a = {};
        a.A = ubf; a.Wa = encb; a.K = 64; a.N = DM;
        a.obf = xbf;
        sgemm64<0><<<gFull, 256, 0, stream>>>(a);
    }

    for (int k = 0; k < NL; ++k) {
        {   // Bu (interleaved re/im cols, gamma-scaled) -> Bubf, + fused chunk-ends
            GemmArgs a = {};
            a.A = xbf; a.Wa = WBb + (size_t)k * DM * DM; a.K = DM; a.N = DM;
            a.obf = Bubf; a.gam = gmt + k * DS;
            a.lamre = lre + k * DS; a.lamim = lim + k * DS; a.carry = carry;
            sgemm64<1><<<gFull, 256, 0, stream>>>(a);
        }
        scan_apply_lb<<<BATCH * NCH, 256, 0, stream>>>((const uint_t*)Bubf,
                                                       lre + k * DS, lim + k * DS, carry,
                                                       (uint_t*)hbf);
        {   // z = Re(h @ C^T) + D*x  -> zbf
            GemmArgs a = {};
            a.A = hbf; a.Wa = Wzb + (size_t)k * DM * DM; a.K = DM; a.N = DM;
            a.obf = zbf; a.xbf_in = xbf; a.Dv = Dp + k * DM;
            sgemm64<2><<<gFull, 256, 0, stream>>>(a);
        }
        {   // xbf += sig(res)*[(z@W1^T)*sigmoid(z@W2^T)]   (bf16 RMW)
            GemmArgs a = {};
            a.A = zbf; a.Wa = W1b + (size_t)k * DM * DM; a.Wb = W2b + (size_t)k * DM * DM;
            a.K = DM; a.N = DM;
            a.obf = xbf; a.xbf_in = xbf; a.resp = res; a.layer = k;
            mgemm<128, 3, 1><<<gFull, 256, 0, stream>>>(a);
        }
    }
    {   // decoder: out = x @ dec^T
        GemmArgs a = {};
        a.A = xbf; a.Wa = decb; a.K = DM; a.N = 64;
        a.of32 = out;
        mgemm<64, 4, 0><<<dim3(MROWS / 128, 1), 256, 0, stream>>>(a);
    }
}

// Round 8
// 369.414 us; speedup vs baseline: 1.0247x; 1.0247x over previous
//
#include <hip/hip_runtime.h>
#include <cmath>

#define DM 512
#define DS 256
#define NL 4
#define BATCH 8
#define SEQ 2048
#define MROWS (BATCH*SEQ)   // 16384
#define LCH 32
#define NCH 64              // LCH*NCH == SEQ

typedef unsigned short ushort_t;
typedef unsigned int uint_t;
typedef __attribute__((ext_vector_type(8))) short short8;
typedef __attribute__((ext_vector_type(4))) float floatx4;

__device__ __forceinline__ float sigmoidf_(float v) { return 1.0f / (1.0f + __expf(-v)); }

__device__ __forceinline__ ushort_t f2bf(float f) {
    union { float f; unsigned int u; } c; c.f = f;
    unsigned int u = c.u;
    u += 0x7fffu + ((u >> 16) & 1u);          // RNE
    return (ushort_t)(u >> 16);
}
__device__ __forceinline__ float bf2f(uint_t h) {
    union { unsigned int u; float f; } c; c.u = (h & 0xffffu) << 16; return c.f;
}
__device__ __forceinline__ uint_t pack2(float a, float b) {
    return (uint_t)f2bf(a) | ((uint_t)f2bf(b) << 16);
}

#define AS1 __attribute__((address_space(1)))
#define AS3 __attribute__((address_space(3)))
__device__ __forceinline__ void gl_lds16(const void* g, void* l) {
    __builtin_amdgcn_global_load_lds((const AS1 uint_t*)g, (AS3 uint_t*)l, 16, 0, 0);
}

// All GEMM arguments in one struct: no positional-arity pitfalls.
struct GemmArgs {
    const ushort_t* A;       // [M,K] bf16
    const ushort_t* Wa;      // [N,K] bf16
    const ushort_t* Wb;      // [N,K] bf16 (DUAL only)
    const ushort_t* xbf_in;  // EPI2/EPI3: bf16 x
    const float* gam;        // EPI1
    const float* Dv;         // EPI2
    float* of32;             // EPI4
    ushort_t* obf;           // EPI0..3
    const float* resp;       // EPI3
    const float* lamre;      // EPI1: lambda tables for fused chunk-end scan
    const float* lamim;      // EPI1
    float* carry;            // EPI1: [B*NCH,512] chunk-end output
    int K;
    int N;
    int layer;
};

// ---------------------------------------------------------------------------
// Structure ledger (R3-R7 post-mortems):
//  + fused chunk-end scan in Bu epilogue, lookback-apply (R4: -4us)
//  + ERND=2 epilogue (R5: -10us)    <- wins = fewer barriers/drains, same occ
//  - T1 XCD swizzle (R3: +20us, L3-resident regime)
//  - 8-wave split   (R6: +10us, per-wave MFMA density fell)
//  - BK=64          (R7: +19us, 64KB LDS -> 2 blocks/CU; m132 replicated)
// R8: singles get a 3-stage counted-vmcnt pipeline (T4) at UNCHANGED 3
// blocks/CU (48KB); per-iter drain vmcnt(0) -> vmcnt(4) + raw s_barrier.
// Dual + decoder stay on the R5-exact mgemm below.
// ---------------------------------------------------------------------------
#define PREFETCH_TILE(it_, buf_)                                                        \
    do {                                                                                \
        const size_t kb_ = (size_t)(it_) * 64;                                          \
        char* dst_ = smem + (buf_) * HALF;                                              \
        gl_lds16(Ap + (size_t)(wid * 16 + lrow) * Kb + kb_, dst_ + wid * 1024);         \
        gl_lds16(Ap + (size_t)((wid + 4) * 16 + lrow) * Kb + kb_,                       \
                 dst_ + (wid + 4) * 1024);                                              \
        gl_lds16(B0p + (size_t)(wid * 16 + lrow) * Kb + kb_, dst_ + AB + wid * 1024);   \
        if constexpr (BN == 128) {                                                      \
            gl_lds16(B0p + (size_t)((wid + 4) * 16 + lrow) * Kb + kb_,                  \
                     dst_ + AB + (wid + 4) * 1024);                                     \
        }                                                                               \
        if constexpr (DUAL) {                                                           \
            gl_lds16(B1p + (size_t)(wid * 16 + lrow) * Kb + kb_,                        \
                     dst_ + AB + BB + wid * 1024);                                      \
            if constexpr (BN == 128) {                                                  \
                gl_lds16(B1p + (size_t)((wid + 4) * 16 + lrow) * Kb + kb_,              \
                         dst_ + AB + BB + (wid + 4) * 1024);                            \
            }                                                                           \
        }                                                                               \
    } while (0)

// R5-exact GEMM: EPI 3 (GLU dual) and 4 (decoder BN=64) only.
template<int BN, int EPI, int DUAL>
__launch_bounds__(256, DUAL ? 2 : 3)
__global__ void mgemm(const GemmArgs p) {
    constexpr int BM = 128;
    constexpr int MT = (BN == 128) ? 4 : 2;
    constexpr int NT = 4;
    constexpr int WROWS = MT * 16;
    constexpr int AB = 8192;                         // A stage bytes (128 x 64B)
    constexpr int BB = (BN == 128) ? 8192 : 4096;
    constexpr int B1B = DUAL ? BB : 0;
    constexpr int HALF = AB + BB + B1B;              // one pipeline stage
    constexpr int EPB = (EPI == 4) ? 0 : 64 * 132 * 4;
    constexpr int SMB = (2 * HALF > EPB) ? 2 * HALF : EPB;
    __shared__ __align__(16) char smem[SMB];

    const int K = p.K, N = p.N;
    const int tid = threadIdx.x, lane = tid & 63, wid = tid >> 6;
    const int wm = (BN == 128) ? (wid & 1) : wid;
    const int wn = (BN == 128) ? (wid >> 1) : 0;
    const int m0 = blockIdx.x * BM, n0 = blockIdx.y * BN;
    const int q = lane >> 4, r16 = lane & 15;
    const int lrow = lane >> 2;
    const size_t Kb = (size_t)K * 2;                 // row bytes
    const char* Ap  = (const char*)p.A  + (size_t)m0 * Kb + (lane & 3) * 16;
    const char* B0p = (const char*)p.Wa + (size_t)n0 * Kb + (lane & 3) * 16;
    const char* B1p = (const char*)p.Wb + (size_t)n0 * Kb + (lane & 3) * 16;

    floatx4 acc0[MT][NT] = {};
    floatx4 acc1[DUAL ? MT : 1][DUAL ? NT : 1] = {};

    const int iters = K >> 5;
    PREFETCH_TILE(0, 0);
    for (int it = 0; it < iters; ++it) {
        __syncthreads();
        if (it + 1 < iters) PREFETCH_TILE(it + 1, (it + 1) & 1);
        const ushort_t* As  = (const ushort_t*)(smem + (it & 1) * HALF);
        const ushort_t* Bs0 = (const ushort_t*)(smem + (it & 1) * HALF + AB);
        const ushort_t* Bs1 = (const ushort_t*)(smem + (it & 1) * HALF + AB + BB);

        short8 af[MT], b0[NT], b1[DUAL ? NT : 1];
#pragma unroll
        for (int i = 0; i < MT; ++i)
            af[i] = *(const short8*)&As[(wm * WROWS + i * 16 + r16) * 32 + q * 8];
#pragma unroll
        for (int j = 0; j < NT; ++j) {
            b0[j] = *(const short8*)&Bs0[(wn * 64 + j * 16 + r16) * 32 + q * 8];
            if constexpr (DUAL)
                b1[j] = *(const short8*)&Bs1[(wn * 64 + j * 16 + r16) * 32 + q * 8];
        }
#pragma unroll
        for (int i = 0; i < MT; ++i)
#pragma unroll
            for (int j = 0; j < NT; ++j) {
                acc0[i][j] = __builtin_amdgcn_mfma_f32_16x16x32_bf16(af[i], b0[j], acc0[i][j], 0, 0, 0);
                if constexpr (DUAL)
                    acc1[i][j] = __builtin_amdgcn_mfma_f32_16x16x32_bf16(af[i], b1[j], acc1[i][j], 0, 0, 0);
            }
    }

    if constexpr (EPI == 4) {
#pragma unroll
        for (int i = 0; i < MT; ++i)
#pragma unroll
            for (int j = 0; j < NT; ++j)
#pragma unroll
                for (int rr = 0; rr < 4; ++rr) {
                    const int row = m0 + wm * WROWS + i * 16 + q * 4 + rr;
                    const int col = wn * 64 + j * 16 + r16;
                    p.of32[(size_t)row * N + col] = acc0[i][j][rr];
                }
        return;
    } else {
        float* eps = (float*)smem;                    // [64][132]
        float rsv = 0.f;
        if constexpr (EPI == 3) rsv = sigmoidf_(p.resp[p.layer]);
        constexpr int ERND = 2;                       // acc i-slabs per eps round

#pragma unroll
        for (int i = 0; i < MT; i += ERND) {
            __syncthreads();
#pragma unroll
            for (int ii = 0; ii < ERND; ++ii) {
#pragma unroll
                for (int j = 0; j < NT; ++j) {
                    const int colt = wn * 64 + j * 16 + r16;
#pragma unroll
                    for (int rr = 0; rr < 4; ++rr) {
                        float v = acc0[i + ii][j][rr];
                        if constexpr (EPI == 3) v = rsv * v * sigmoidf_(acc1[i + ii][j][rr]);
                        eps[(ii * 32 + wm * 16 + q * 4 + rr) * 132 + colt] = v;
                    }
                }
            }
            __syncthreads();
            const int row_r = tid >> 3, colg = (tid & 7) * 16;
#pragma unroll
            for (int ii = 0; ii < ERND; ++ii) {
                const int lr = (row_r >> 4) * 64 + (i + ii) * 16 + (row_r & 15);
                const int grow = m0 + lr;
                const int gcol = n0 + colg;
                float4 f[4];
#pragma unroll
                for (int c = 0; c < 4; ++c)
                    f[c] = *(float4*)&eps[(ii * 32 + row_r) * 132 + colg + c * 4];
                const size_t ob = (size_t)grow * N + gcol;

                if constexpr (EPI == 3) {
                    uint_t xp[8];
                    *(uint4*)(xp)     = *(const uint4*)(p.xbf_in + ob);
                    *(uint4*)(xp + 4) = *(const uint4*)(p.xbf_in + ob + 8);
#pragma unroll
                    for (int c = 0; c < 4; ++c) {
                        f[c].x += bf2f(xp[2 * c]);
                        f[c].y += bf2f(xp[2 * c] >> 16);
                        f[c].z += bf2f(xp[2 * c + 1]);
                        f[c].w += bf2f(xp[2 * c + 1] >> 16);
                    }
                }
                uint4 p0, p1;
                p0.x = pack2(f[0].x, f[0].y); p0.y = pack2(f[0].z, f[0].w);
                p0.z = pack2(f[1].x, f[1].y); p0.w = pack2(f[1].z, f[1].w);
                p1.x = pack2(f[2].x, f[2].y); p1.y = pack2(f[2].z, f[2].w);
                p1.z = pack2(f[3].x, f[3].y); p1.w = pack2(f[3].z, f[3].w);
                *(uint4*)(p.obf + ob) = p0;
                *(uint4*)(p.obf + ob + 8) = p1;
            }
        }
    }
}

// ---------------------------------------------------------------------------
// Pipelined single-B GEMM (EPI 0 encoder / 1 Bu / 2 z): BK=32, 3-stage LDS
// rotation (48KB -> occupancy-3 PRESERVED, unlike R7's 64KB), prefetch
// distance 2, counted vmcnt (T4): per-iter `s_waitcnt vmcnt(4)` + raw
// s_barrier keeps the next stage's 4 global_load_lds in flight across the
// barrier instead of draining to 0.
// Safety: stage it+2 overwrites the buffer consumed at it-1; it is issued
// after barrier(it), which every wave reaches only after compute(it-1) (WAR
// ok). vmcnt waits the OLDEST 4 ops (m135 in-order), so stage it's writes
// are complete before compute(it) (RAW ok). Epilogue = R5-exact.
// ---------------------------------------------------------------------------
template<int EPI>
__launch_bounds__(256, 3)
__global__ void sgemm_p(const GemmArgs p) {
    constexpr int BM = 128;
    constexpr int MT = 4, NT = 4;
    constexpr int AB = 8192, BB = 8192;
    constexpr int HALF = AB + BB;                    // 16K / stage
    constexpr int EPB = (EPI == 1) ? (32 * 132 * 4 + 128 * 66 * 4) : 64 * 132 * 4;
    constexpr int SMB = (3 * HALF > EPB) ? 3 * HALF : EPB;   // <= 50.7KB -> occ 3
    __shared__ __align__(16) char smem[SMB];

    const int K = p.K, N = p.N;
    const int tid = threadIdx.x, lane = tid & 63, wid = tid >> 6;
    const int wm = wid & 1, wn = wid >> 1;           // 2x2 wave grid, 64x64/wave
    const int m0 = blockIdx.x * BM, n0 = blockIdx.y * 128;
    const int q = lane >> 4, r16 = lane & 15;
    const int lrow = lane >> 2;
    const size_t Kb = (size_t)K * 2;                 // row bytes
    const char* Ap  = (const char*)p.A  + (size_t)m0 * Kb + (lane & 3) * 16;
    const char* B0p = (const char*)p.Wa + (size_t)n0 * Kb + (lane & 3) * 16;

    floatx4 acc0[MT][NT] = {};

#define PFP(it_, buf_)                                                                  \
    do {                                                                                \
        const size_t kb_ = (size_t)(it_) * 64;                                          \
        char* dst_ = smem + (buf_) * HALF;                                              \
        gl_lds16(Ap + (size_t)(wid * 16 + lrow) * Kb + kb_, dst_ + wid * 1024);         \
        gl_lds16(Ap + (size_t)((wid + 4) * 16 + lrow) * Kb + kb_,                       \
                 dst_ + (wid + 4) * 1024);                                              \
        gl_lds16(B0p + (size_t)(wid * 16 + lrow) * Kb + kb_, dst_ + AB + wid * 1024);   \
        gl_lds16(B0p + (size_t)((wid + 4) * 16 + lrow) * Kb + kb_,                      \
                 dst_ + AB + (wid + 4) * 1024);                                         \
    } while (0)

    const int iters = K >> 5;
    PFP(0, 0);
    if (iters > 1) PFP(1, 1);
    int b0i = 0, b2i = 2;                            // current / prefetch bufs
    for (int it = 0; it < iters; ++it) {
        if (it + 1 < iters) asm volatile("s_waitcnt vmcnt(4)" ::: "memory");
        else                asm volatile("s_waitcnt vmcnt(0)" ::: "memory");
        __builtin_amdgcn_s_barrier();
        if (it + 2 < iters) PFP(it + 2, b2i);
        const ushort_t* As  = (const ushort_t*)(smem + b0i * HALF);
        const ushort_t* Bs0 = (const ushort_t*)(smem + b0i * HALF + AB);

        short8 af[MT], b0[NT];
#pragma unroll
        for (int i = 0; i < MT; ++i)
            af[i] = *(const short8*)&As[(wm * 64 + i * 16 + r16) * 32 + q * 8];
#pragma unroll
        for (int j = 0; j < NT; ++j)
            b0[j] = *(const short8*)&Bs0[(wn * 64 + j * 16 + r16) * 32 + q * 8];
#pragma unroll
        for (int i = 0; i < MT; ++i)
#pragma unroll
            for (int j = 0; j < NT; ++j)
                acc0[i][j] = __builtin_amdgcn_mfma_f32_16x16x32_bf16(af[i], b0[j], acc0[i][j], 0, 0, 0);

        b0i = (b0i == 2) ? 0 : b0i + 1;
        b2i = (b2i == 2) ? 0 : b2i + 1;
    }
#undef PFP

    // ---- epilogue (R5-exact): LDS transpose + bf16 pack ----
    float* eps = (float*)smem;                       // [ERND*32][132]
    uint_t* zst = (uint_t*)(smem + 32 * 132 * 4);    // EPI1 only: [128][66]
    constexpr int ERND = (EPI == 1) ? 1 : 2;

#pragma unroll
    for (int i = 0; i < MT; i += ERND) {
        __syncthreads();
#pragma unroll
        for (int ii = 0; ii < ERND; ++ii) {
#pragma unroll
            for (int j = 0; j < NT; ++j) {
                const int colt = wn * 64 + j * 16 + r16;
#pragma unroll
                for (int rr = 0; rr < 4; ++rr) {
                    float v = acc0[i + ii][j][rr];
                    if constexpr (EPI == 1) v *= p.gam[(n0 + colt) >> 1];
                    eps[(ii * 32 + wm * 16 + q * 4 + rr) * 132 + colt] = v;
                }
            }
        }
        __syncthreads();
        const int row_r = tid >> 3, colg = (tid & 7) * 16;
#pragma unroll
        for (int ii = 0; ii < ERND; ++ii) {
            const int lr = (row_r >> 4) * 64 + (i + ii) * 16 + (row_r & 15);
            const int grow = m0 + lr;
            const int gcol = n0 + colg;
            float4 f[4];
#pragma unroll
            for (int c = 0; c < 4; ++c)
                f[c] = *(float4*)&eps[(ii * 32 + row_r) * 132 + colg + c * 4];
            const size_t ob = (size_t)grow * N + gcol;

            if constexpr (EPI == 2) {
                uint_t xp[8];
                *(uint4*)(xp)     = *(const uint4*)(p.xbf_in + ob);
                *(uint4*)(xp + 4) = *(const uint4*)(p.xbf_in + ob + 8);
#pragma unroll
                for (int c = 0; c < 4; ++c) {
                    float4 dv = *(const float4*)(p.Dv + gcol + c * 4);
                    f[c].x += dv.x * bf2f(xp[2 * c]);
                    f[c].y += dv.y * bf2f(xp[2 * c] >> 16);
                    f[c].z += dv.z * bf2f(xp[2 * c + 1]);
                    f[c].w += dv.w * bf2f(xp[2 * c + 1] >> 16);
                }
            }
            uint4 p0, p1;
            p0.x = pack2(f[0].x, f[0].y); p0.y = pack2(f[0].z, f[0].w);
            p0.z = pack2(f[1].x, f[1].y); p0.w = pack2(f[1].z, f[1].w);
            p1.x = pack2(f[2].x, f[2].y); p1.y = pack2(f[2].z, f[2].w);
            p1.z = pack2(f[3].x, f[3].y); p1.w = pack2(f[3].z, f[3].w);
            *(uint4*)(p.obf + ob) = p0;
            *(uint4*)(p.obf + ob + 8) = p1;
            if constexpr (EPI == 1) {
                const int c0 = colg >> 1;
                *(uint4*)&zst[lr * 66 + c0]     = p0;
                *(uint4*)&zst[lr * 66 + c0 + 4] = p1;
            }
        }
    }

    if constexpr (EPI == 1) {
        // fused chunk-end scan: thread t -> chunk c4 (of 4), local state s6
        __syncthreads();
        const int c4 = tid >> 6, s6 = tid & 63;
        const int sg = (n0 >> 1) + s6;                 // global state
        const float lr_ = p.lamre[sg], li_ = p.lamim[sg];
        float hr = 0.f, hi = 0.f;
#pragma unroll 8
        for (int i2 = 0; i2 < LCH; ++i2) {
            uint_t uu = zst[(c4 * LCH + i2) * 66 + s6];
            float br = bf2f(uu), bi = bf2f(uu >> 16);
            float nr = fmaf(lr_, hr, fmaf(-li_, hi, br));
            float ni = fmaf(lr_, hi, fmaf(li_, hr, bi));
            hr = nr; hi = ni;
        }
        const int b = m0 >> 11;                        // m0 / SEQ
        const int cblk = ((m0 & (SEQ - 1)) >> 5) + c4; // chunk index in seq
        const size_t cb = (size_t)(b * NCH + cblk) * 512 + sg;
        p.carry[cb] = hr; p.carry[cb + DS] = hi;
    }
}

// ---------------------------------------------------------------------------
// Single prep kernel: all weight bf16 packing + u cast + lambda/gamma tables.
// ---------------------------------------------------------------------------
__global__ void prep_all(const float* __restrict__ u, const float* __restrict__ enc,
                         const float* __restrict__ dec, const float* __restrict__ nu,
                         const float* __restrict__ th,
                         const float* __restrict__ Bre, const float* __restrict__ Bim,
                         const float* __restrict__ Cre, const float* __restrict__ Cim,
                         const float* __restrict__ W1, const float* __restrict__ W2,
                         ushort_t* __restrict__ WBb, ushort_t* __restrict__ Wzb,
                         ushort_t* __restrict__ W1b, ushort_t* __restrict__ W2b,
                         ushort_t* __restrict__ encb, ushort_t* __restrict__ decb,
                         ushort_t* __restrict__ ubf,
                         float* __restrict__ lre, float* __restrict__ lim,
                         float* __restrict__ gm) {
    const int idx = blockIdx.x * 256 + threadIdx.x;   // 0..1M-1
    const int k = idx & 511, n = (idx >> 9) & 511, l = idx >> 18;
    {
        const int s = n >> 1, part = n & 1;
        const float* src = part ? Bim : Bre;
        WBb[idx] = f2bf(src[((size_t)l * DS + s) * DM + k]);
    }
    {
        const int s = k >> 1, part = k & 1;
        float v = part ? -Cim[((size_t)l * DM + n) * DS + s]
                       :  Cre[((size_t)l * DM + n) * DS + s];
        Wzb[idx] = f2bf(v);
    }
    W1b[idx] = f2bf(W1[idx]);
    W2b[idx] = f2bf(W2[idx]);
    ubf[idx] = f2bf(u[idx]);
    if (idx < DM * 64) { encb[idx] = f2bf(enc[idx]); decb[idx] = f2bf(dec[idx]); }
    if (idx < NL * DS) {
        float a = expf(-expf(nu[idx])), t = expf(th[idx]);
        lre[idx] = a * cosf(t);
        lim[idx] = a * sinf(t);
        gm[idx] = sqrtf(fmaxf(0.f, 1.f - a * a));
    }
}

// ---------------------------------------------------------------------------
// Lookback apply — NO inter-block waiting (R2 post-mortem: agent-scope spin
// cost ~100us). Chunk-end carries are produced by the Bu-GEMM epilogue.
// Rebuilds prefix g from a depth-12 truncated lookback over carry
// (|lam^32| <= 0.194 -> 0.194^12 ~ 3e-9 truncation, far below bf16 noise;
// arithmetic verified R1-R7), then applies + writes h. Deterministic.
// ---------------------------------------------------------------------------
__global__ __launch_bounds__(256) void scan_apply_lb(
        const uint_t* __restrict__ Bu, const float* __restrict__ lre_,
        const float* __restrict__ lim_, const float* __restrict__ carry,
        uint_t* __restrict__ h) {
    const int s = threadIdx.x;
    const int blk = blockIdx.x, b = blk >> 6, c = blk & 63;
    const float lre = lre_[s], lim = lim_[s];

    // lookback: g = state at end of chunk c-1 (truncated geometric sum)
    float gre = 0.f, gim = 0.f;
    if (c > 0) {
        float are = lre, aim = lim;          // lam^32 (5 squarings)
#pragma unroll
        for (int t = 0; t < 5; ++t) {
            float nr = are * are - aim * aim, ni = 2.f * are * aim;
            are = nr; aim = ni;
        }
        const int depth = (c < 12) ? c : 12;
        float pwr = 1.f, pwi = 0.f;
        for (int j = c - 1; j >= c - depth; --j) {
            const size_t jb = (size_t)(b * NCH + j) * 512 + s;
            float er = carry[jb], ei = carry[jb + DS];
            gre = fmaf(pwr, er, fmaf(-pwi, ei, gre));
            gim = fmaf(pwr, ei, fmaf(pwi, er, gim));
            float nr = pwr * are - pwi * aim, ni = pwr * aim + pwi * are;
            pwr = nr; pwi = ni;
        }
    }

    // apply: rerun recurrence from g, write h
    float hr = gre, hi = gim;
    size_t base = ((size_t)b * SEQ + (size_t)c * LCH) * DS + s;
#pragma unroll 8
    for (int i = 0; i < LCH; ++i, base += DS) {
        uint_t uu = Bu[base];
        float br = bf2f(uu), bi = bf2f(uu >> 16);
        float nr = fmaf(lre, hr, fmaf(-lim, hi, br));
        float ni = fmaf(lre, hi, fmaf(lim, hr, bi));
        hr = nr; hi = ni;
        h[base] = pack2(hr, hi);
    }
}

// ---------------------------------------------------------------------------
extern "C" void kernel_launch(void* const* d_in, const int* in_sizes, int n_in,
                              void* d_out, int out_size, void* d_ws, size_t ws_size,
                              hipStream_t stream) {
    const float* u   = (const float*)d_in[0];
    const float* enc = (const float*)d_in[1];
    const float* dec = (const float*)d_in[2];
    const float* nu  = (const float*)d_in[3];
    const float* th  = (const float*)d_in[4];
    const float* Bre = (const float*)d_in[5];
    const float* Bim = (const float*)d_in[6];
    const float* Cre = (const float*)d_in[7];
    const float* Cim = (const float*)d_in[8];
    const float* Dp  = (const float*)d_in[9];
    const float* W1  = (const float*)d_in[10];
    const float* W2  = (const float*)d_in[11];
    const float* res = (const float*)d_in[12];
    float* out = (float*)d_out;

    const size_t MD = (size_t)MROWS * DM;
    float* carry = (float*)d_ws;                         // [8*64,512] fp32
    float* lre  = carry + (size_t)BATCH * NCH * 512;
    float* lim  = lre + NL * DS;
    float* gmt  = lim + NL * DS;
    ushort_t* xbf  = (ushort_t*)(gmt + NL * DS);         // bf16 [16384,512] each:
    ushort_t* Bubf = xbf + MD;
    ushort_t* hbf  = Bubf + MD;
    ushort_t* zbf  = hbf + MD;
    ushort_t* ubf  = zbf;                                // alias: z written after u consumed
    ushort_t* WBb  = zbf + MD;                           // weights, 4x512x512 bf16 each:
    ushort_t* Wzb  = WBb + (size_t)NL * DM * DM;
    ushort_t* W1b  = Wzb + (size_t)NL * DM * DM;
    ushort_t* W2b  = W1b + (size_t)NL * DM * DM;
    ushort_t* encb = W2b + (size_t)NL * DM * DM;         // 512x64
    ushort_t* decb = encb + DM * 64;                     // 64x512

    prep_all<<<NL * DM * DM / 256, 256, 0, stream>>>(
        u, enc, dec, nu, th, Bre, Bim, Cre, Cim, W1, W2,
        WBb, Wzb, W1b, W2b, encb, decb, ubf, lre, lim, gmt);

    const dim3 gFull(MROWS / 128, DM / 128);

    // encoder: xbf = bf16(u @ enc^T)
    {
        GemmArgs a = {};
        a.A = ubf; a.Wa = encb; a.K = 64; a.N = DM;
        a.obf = xbf;
        sgemm_p<0><<<gFull, 256, 0, stream>>>(a);
    }

    for (int k = 0; k < NL; ++k) {
        {   // Bu (interleaved re/im cols, gamma-scaled) -> Bubf, + fused chunk-ends
            GemmArgs a = {};
            a.A = xbf; a.Wa = WBb + (size_t)k * DM * DM; a.K = DM; a.N = DM;
            a.obf = Bubf; a.gam = gmt + k * DS;
            a.lamre = lre + k * DS; a.lamim = lim + k * DS; a.carry = carry;
            sgemm_p<1><<<gFull, 256, 0, stream>>>(a);
        }
        scan_apply_lb<<<BATCH * NCH, 256, 0, stream>>>((const uint_t*)Bubf,
                                                       lre + k * DS, lim + k * DS, carry,
                                                       (uint_t*)hbf);
        {   // z = Re(h @ C^T) + D*x  -> zbf
            GemmArgs a = {};
            a.A = hbf; a.Wa = Wzb + (size_t)k * DM * DM; a.K = DM; a.N = DM;
            a.obf = zbf; a.xbf_in = xbf; a.Dv = Dp + k * DM;
            sgemm_p<2><<<gFull, 256, 0, stream>>>(a);
        }
        {   // xbf += sig(res)*[(z@W1^T)*sigmoid(z@W2^T)]   (bf16 RMW)
            GemmArgs a = {};
            a.A = zbf; a.Wa = W1b + (size_t)k * DM * DM; a.Wb = W2b + (size_t)k * DM * DM;
            a.K = DM; a.N = DM;
            a.obf = xbf; a.xbf_in = xbf; a.resp = res; a.layer = k;
            mgemm<128, 3, 1><<<gFull, 256, 0, stream>>>(a);
        }
    }
    {   // decoder: out = x @ dec^T
        GemmArgs a = {};
        a.A = xbf; a.Wa = decb; a.K = DM; a.N = 64;
        a.of32 = out;
        mgemm<64, 4, 0><<<dim3(MROWS / 128, 1), 256, 0, stream>>>(a);
    }
}

// Round 9
// 358.367 us; speedup vs baseline: 1.0563x; 1.0308x over previous
//
#include <hip/hip_runtime.h>
#include <cmath>

#define DM 512
#define DS 256
#define NL 4
#define BATCH 8
#define SEQ 2048
#define MROWS (BATCH*SEQ)   // 16384
#define LCH 32
#define NCH 64              // LCH*NCH == SEQ

typedef unsigned short ushort_t;
typedef unsigned int uint_t;
typedef __attribute__((ext_vector_type(8))) short short8;
typedef __attribute__((ext_vector_type(4))) float floatx4;

__device__ __forceinline__ float sigmoidf_(float v) { return 1.0f / (1.0f + __expf(-v)); }

__device__ __forceinline__ ushort_t f2bf(float f) {
    union { float f; unsigned int u; } c; c.f = f;
    unsigned int u = c.u;
    u += 0x7fffu + ((u >> 16) & 1u);          // RNE
    return (ushort_t)(u >> 16);
}
__device__ __forceinline__ float bf2f(uint_t h) {
    union { unsigned int u; float f; } c; c.u = (h & 0xffffu) << 16; return c.f;
}
__device__ __forceinline__ uint_t pack2(float a, float b) {
    return (uint_t)f2bf(a) | ((uint_t)f2bf(b) << 16);
}

#define AS1 __attribute__((address_space(1)))
#define AS3 __attribute__((address_space(3)))
__device__ __forceinline__ void gl_lds16(const void* g, void* l) {
    __builtin_amdgcn_global_load_lds((const AS1 uint_t*)g, (AS3 uint_t*)l, 16, 0, 0);
}

// All GEMM arguments in one struct: no positional-arity pitfalls.
struct GemmArgs {
    const ushort_t* A;       // [M,K] bf16
    const ushort_t* Wa;      // [N,K] bf16
    const ushort_t* Wb;      // [N,K] bf16 (DUAL only)
    const ushort_t* xbf_in;  // EPI2/EPI3: bf16 x
    const float* gam;        // EPI1
    const float* Dv;         // EPI2
    float* of32;             // EPI4
    ushort_t* obf;           // EPI0..3
    const float* resp;       // EPI3
    const float* lamre;      // EPI1: lambda tables for fused chunk-end scan
    const float* lamim;      // EPI1
    float* carry;            // EPI1: [B*NCH,512] chunk-end output
    int K;
    int N;
    int layer;
};

// ---------------------------------------------------------------------------
// FINAL (R9 = R5-exact revert; best verified 359.6us).
// Structure ledger (R0-R8):
//  + fused chunk-end scan in Bu epilogue + lookback-apply (R4: -4us)
//  + ERND=2 epilogue for EPI0/2/3 (R5: -10us)
//  - T1 XCD swizzle   (R3: +20us — L3-resident regime, no HBM refetch to
//    save; swizzle thrashed per-XCD L2 with 4 B-panels + A in 4MB)
//  - 8-wave/512t      (R6: +10us — per-wave MFMA density fell, ds:MFMA
//    0.5->0.75; 8-wave barriers cost more than occupancy bought)
//  - BK=64            (R7: +19us — 64KB LDS dropped 3->2 blocks/CU; m132)
//  - counted-vmcnt 3-stage (R8: +10us — pipeline bookkeeping > drain saved;
//    m131 replicated at short K)
// Conclusion: wins = barrier/drain-COUNT reductions at constant occupancy;
// K-loop internals of the 2-phase template are at their floor (m131-m140).
//
// bf16 MFMA GEMM, BM=BN=128, 4-wave/256t, double-buffered global_load_lds
// staging, LDS-transpose epilogue. O = A[M,K] @ W[N,K]^T. EPI:
//  0: encoder  -> obf = bf16(acc)
//  1: Bu       -> obf = bf16(acc * gam[col>>1])  (interleaved re/im cols)
//                 + FUSED chunk-end scan via zst stash (replaces scan_ends;
//                 identical numerics: scans the same rounded bf16).
//  2: z        -> obf = bf16(acc + Dv[col]*bf2f(xbf_in[row,col]))
//  3: GLU dual -> obf = bf16(bf2f(xbf_in) + sigmoid(resp[l])*acc0*sigmoid(acc1))
//  4: plain    -> of32 = acc   (decoder, BN=64, direct store)
// launch_bounds 3 (single) / 2 (dual): dual needs >=128 VGPR for acc alone.
// EPI1 keeps 32-row eps rounds (zst stash + occupancy-3: 50.6KB*3 < 160KB).
// ---------------------------------------------------------------------------
#define PREFETCH_TILE(it_, buf_)                                                        \
    do {                                                                                \
        const size_t kb_ = (size_t)(it_) * 64;                                          \
        char* dst_ = smem + (buf_) * HALF;                                              \
        gl_lds16(Ap + (size_t)(wid * 16 + lrow) * Kb + kb_, dst_ + wid * 1024);         \
        gl_lds16(Ap + (size_t)((wid + 4) * 16 + lrow) * Kb + kb_,                       \
                 dst_ + (wid + 4) * 1024);                                              \
        gl_lds16(B0p + (size_t)(wid * 16 + lrow) * Kb + kb_, dst_ + AB + wid * 1024);   \
        if constexpr (BN == 128) {                                                      \
            gl_lds16(B0p + (size_t)((wid + 4) * 16 + lrow) * Kb + kb_,                  \
                     dst_ + AB + (wid + 4) * 1024);                                     \
        }                                                                               \
        if constexpr (DUAL) {                                                           \
            gl_lds16(B1p + (size_t)(wid * 16 + lrow) * Kb + kb_,                        \
                     dst_ + AB + BB + wid * 1024);                                      \
            if constexpr (BN == 128) {                                                  \
                gl_lds16(B1p + (size_t)((wid + 4) * 16 + lrow) * Kb + kb_,              \
                         dst_ + AB + BB + (wid + 4) * 1024);                            \
            }                                                                           \
        }                                                                               \
    } while (0)

template<int BN, int EPI, int DUAL>
__launch_bounds__(256, DUAL ? 2 : 3)
__global__ void mgemm(const GemmArgs p) {
    constexpr int BM = 128;
    constexpr int MT = (BN == 128) ? 4 : 2;
    constexpr int NT = 4;
    constexpr int WROWS = MT * 16;
    constexpr int AB = 8192;                         // A stage bytes (128 x 64B)
    constexpr int BB = (BN == 128) ? 8192 : 4096;
    constexpr int B1B = DUAL ? BB : 0;
    constexpr int HALF = AB + BB + B1B;              // one pipeline stage
    // epilogue LDS: EPI1 = [32][132] eps + [128][66] zst; EPI0/2/3 = [64][132]
    constexpr int EPB = (EPI == 4) ? 0
                      : (EPI == 1) ? (32 * 132 * 4 + 128 * 66 * 4)
                      : 64 * 132 * 4;
    constexpr int SMB = (2 * HALF > EPB) ? 2 * HALF : EPB;
    __shared__ __align__(16) char smem[SMB];

    const int K = p.K, N = p.N;
    const int tid = threadIdx.x, lane = tid & 63, wid = tid >> 6;
    const int wm = (BN == 128) ? (wid & 1) : wid;
    const int wn = (BN == 128) ? (wid >> 1) : 0;
    const int m0 = blockIdx.x * BM, n0 = blockIdx.y * BN;
    const int q = lane >> 4, r16 = lane & 15;
    const int lrow = lane >> 2;
    const size_t Kb = (size_t)K * 2;                 // row bytes
    const char* Ap  = (const char*)p.A  + (size_t)m0 * Kb + (lane & 3) * 16;
    const char* B0p = (const char*)p.Wa + (size_t)n0 * Kb + (lane & 3) * 16;
    const char* B1p = (const char*)p.Wb + (size_t)n0 * Kb + (lane & 3) * 16;

    floatx4 acc0[MT][NT] = {};
    floatx4 acc1[DUAL ? MT : 1][DUAL ? NT : 1] = {};

    const int iters = K >> 5;
    PREFETCH_TILE(0, 0);
    for (int it = 0; it < iters; ++it) {
        __syncthreads();
        if (it + 1 < iters) PREFETCH_TILE(it + 1, (it + 1) & 1);
        const ushort_t* As  = (const ushort_t*)(smem + (it & 1) * HALF);
        const ushort_t* Bs0 = (const ushort_t*)(smem + (it & 1) * HALF + AB);
        const ushort_t* Bs1 = (const ushort_t*)(smem + (it & 1) * HALF + AB + BB);

        short8 af[MT], b0[NT], b1[DUAL ? NT : 1];
#pragma unroll
        for (int i = 0; i < MT; ++i)
            af[i] = *(const short8*)&As[(wm * WROWS + i * 16 + r16) * 32 + q * 8];
#pragma unroll
        for (int j = 0; j < NT; ++j) {
            b0[j] = *(const short8*)&Bs0[(wn * 64 + j * 16 + r16) * 32 + q * 8];
            if constexpr (DUAL)
                b1[j] = *(const short8*)&Bs1[(wn * 64 + j * 16 + r16) * 32 + q * 8];
        }
#pragma unroll
        for (int i = 0; i < MT; ++i)
#pragma unroll
            for (int j = 0; j < NT; ++j) {
                acc0[i][j] = __builtin_amdgcn_mfma_f32_16x16x32_bf16(af[i], b0[j], acc0[i][j], 0, 0, 0);
                if constexpr (DUAL)
                    acc1[i][j] = __builtin_amdgcn_mfma_f32_16x16x32_bf16(af[i], b1[j], acc1[i][j], 0, 0, 0);
            }
    }

    if constexpr (EPI == 4) {
#pragma unroll
        for (int i = 0; i < MT; ++i)
#pragma unroll
            for (int j = 0; j < NT; ++j)
#pragma unroll
                for (int rr = 0; rr < 4; ++rr) {
                    const int row = m0 + wm * WROWS + i * 16 + q * 4 + rr;
                    const int col = wn * 64 + j * 16 + r16;
                    p.of32[(size_t)row * N + col] = acc0[i][j][rr];
                }
        return;
    } else {
        float* eps = (float*)smem;                    // [ERND*32][132]
        uint_t* zst = (uint_t*)(smem + 32 * 132 * 4); // EPI1 only: [128][66]
        float rsv = 0.f;
        if constexpr (EPI == 3) rsv = sigmoidf_(p.resp[p.layer]);
        constexpr int ERND = (EPI == 1) ? 1 : 2;      // acc i-slabs per eps round

#pragma unroll
        for (int i = 0; i < MT; i += ERND) {
            __syncthreads();
#pragma unroll
            for (int ii = 0; ii < ERND; ++ii) {
#pragma unroll
                for (int j = 0; j < NT; ++j) {
                    const int colt = wn * 64 + j * 16 + r16;
#pragma unroll
                    for (int rr = 0; rr < 4; ++rr) {
                        float v = acc0[i + ii][j][rr];
                        if constexpr (EPI == 1) v *= p.gam[(n0 + colt) >> 1];
                        if constexpr (EPI == 3) v = rsv * v * sigmoidf_(acc1[i + ii][j][rr]);
                        eps[(ii * 32 + wm * 16 + q * 4 + rr) * 132 + colt] = v;
                    }
                }
            }
            __syncthreads();
            const int row_r = tid >> 3, colg = (tid & 7) * 16;
#pragma unroll
            for (int ii = 0; ii < ERND; ++ii) {
                const int lr = (row_r >> 4) * 64 + (i + ii) * 16 + (row_r & 15);  // local row
                const int grow = m0 + lr;
                const int gcol = n0 + colg;
                float4 f[4];
#pragma unroll
                for (int c = 0; c < 4; ++c)
                    f[c] = *(float4*)&eps[(ii * 32 + row_r) * 132 + colg + c * 4];
                const size_t ob = (size_t)grow * N + gcol;

                if constexpr (EPI == 2) {
                    uint_t xp[8];
                    *(uint4*)(xp)     = *(const uint4*)(p.xbf_in + ob);
                    *(uint4*)(xp + 4) = *(const uint4*)(p.xbf_in + ob + 8);
#pragma unroll
                    for (int c = 0; c < 4; ++c) {
                        float4 dv = *(const float4*)(p.Dv + gcol + c * 4);
                        f[c].x += dv.x * bf2f(xp[2 * c]);
                        f[c].y += dv.y * bf2f(xp[2 * c] >> 16);
                        f[c].z += dv.z * bf2f(xp[2 * c + 1]);
                        f[c].w += dv.w * bf2f(xp[2 * c + 1] >> 16);
                    }
                } else if constexpr (EPI == 3) {
                    uint_t xp[8];
                    *(uint4*)(xp)     = *(const uint4*)(p.xbf_in + ob);
                    *(uint4*)(xp + 4) = *(const uint4*)(p.xbf_in + ob + 8);
#pragma unroll
                    for (int c = 0; c < 4; ++c) {
                        f[c].x += bf2f(xp[2 * c]);
                        f[c].y += bf2f(xp[2 * c] >> 16);
                        f[c].z += bf2f(xp[2 * c + 1]);
                        f[c].w += bf2f(xp[2 * c + 1] >> 16);
                    }
                }
                uint4 p0, p1;
                p0.x = pack2(f[0].x, f[0].y); p0.y = pack2(f[0].z, f[0].w);
                p0.z = pack2(f[1].x, f[1].y); p0.w = pack2(f[1].z, f[1].w);
                p1.x = pack2(f[2].x, f[2].y); p1.y = pack2(f[2].z, f[2].w);
                p1.z = pack2(f[3].x, f[3].y); p1.w = pack2(f[3].z, f[3].w);
                *(uint4*)(p.obf + ob) = p0;
                *(uint4*)(p.obf + ob + 8) = p1;
                if constexpr (EPI == 1) {
                    // stash packed (re,im) pairs: local row lr, local states colg/2..+7
                    const int c0 = colg >> 1;
                    *(uint4*)&zst[lr * 66 + c0]     = p0;
                    *(uint4*)&zst[lr * 66 + c0 + 4] = p1;
                }
            }
        }

        if constexpr (EPI == 1) {
            // fused chunk-end scan: thread t -> chunk c4 (of 4), local state s6
            __syncthreads();
            const int c4 = tid >> 6, s6 = tid & 63;
            const int sg = (n0 >> 1) + s6;                 // global state
            const float lr_ = p.lamre[sg], li_ = p.lamim[sg];
            float hr = 0.f, hi = 0.f;
#pragma unroll 8
            for (int i2 = 0; i2 < LCH; ++i2) {
                uint_t uu = zst[(c4 * LCH + i2) * 66 + s6];
                float br = bf2f(uu), bi = bf2f(uu >> 16);
                float nr = fmaf(lr_, hr, fmaf(-li_, hi, br));
                float ni = fmaf(lr_, hi, fmaf(li_, hr, bi));
                hr = nr; hi = ni;
            }
            const int b = m0 >> 11;                        // m0 / SEQ
            const int cblk = ((m0 & (SEQ - 1)) >> 5) + c4; // chunk index in seq
            const size_t cb = (size_t)(b * NCH + cblk) * 512 + sg;
            p.carry[cb] = hr; p.carry[cb + DS] = hi;
        }
    }
}

// ---------------------------------------------------------------------------
// Single prep kernel: all weight bf16 packing + u cast + lambda/gamma tables.
// ---------------------------------------------------------------------------
__global__ void prep_all(const float* __restrict__ u, const float* __restrict__ enc,
                         const float* __restrict__ dec, const float* __restrict__ nu,
                         const float* __restrict__ th,
                         const float* __restrict__ Bre, const float* __restrict__ Bim,
                         const float* __restrict__ Cre, const float* __restrict__ Cim,
                         const float* __restrict__ W1, const float* __restrict__ W2,
                         ushort_t* __restrict__ WBb, ushort_t* __restrict__ Wzb,
                         ushort_t* __restrict__ W1b, ushort_t* __restrict__ W2b,
                         ushort_t* __restrict__ encb, ushort_t* __restrict__ decb,
                         ushort_t* __restrict__ ubf,
                         float* __restrict__ lre, float* __restrict__ lim,
                         float* __restrict__ gm) {
    const int idx = blockIdx.x * 256 + threadIdx.x;   // 0..1M-1
    const int k = idx & 511, n = (idx >> 9) & 511, l = idx >> 18;
    {
        const int s = n >> 1, part = n & 1;
        const float* src = part ? Bim : Bre;
        WBb[idx] = f2bf(src[((size_t)l * DS + s) * DM + k]);
    }
    {
        const int s = k >> 1, part = k & 1;
        float v = part ? -Cim[((size_t)l * DM + n) * DS + s]
                       :  Cre[((size_t)l * DM + n) * DS + s];
        Wzb[idx] = f2bf(v);
    }
    W1b[idx] = f2bf(W1[idx]);
    W2b[idx] = f2bf(W2[idx]);
    ubf[idx] = f2bf(u[idx]);
    if (idx < DM * 64) { encb[idx] = f2bf(enc[idx]); decb[idx] = f2bf(dec[idx]); }
    if (idx < NL * DS) {
        float a = expf(-expf(nu[idx])), t = expf(th[idx]);
        lre[idx] = a * cosf(t);
        lim[idx] = a * sinf(t);
        gm[idx] = sqrtf(fmaxf(0.f, 1.f - a * a));
    }
}

// ---------------------------------------------------------------------------
// Lookback apply — NO inter-block waiting (R2 post-mortem: agent-scope spin
// cost ~100us). Chunk-end carries are produced by the Bu-GEMM epilogue
// (fused scan_ends). This kernel rebuilds prefix g from a depth-12 truncated
// lookback over carry (|lam^32| <= 0.194 -> 0.194^12 ~ 3e-9 truncation, far
// below bf16 noise; arithmetic verified R1-R8), then applies + writes h.
// Deterministic, no atomics, no fences.
// ---------------------------------------------------------------------------
__global__ __launch_bounds__(256) void scan_apply_lb(
        const uint_t* __restrict__ Bu, const float* __restrict__ lre_,
        const float* __restrict__ lim_, const float* __restrict__ carry,
        uint_t* __restrict__ h) {
    const int s = threadIdx.x;
    const int blk = blockIdx.x, b = blk >> 6, c = blk & 63;
    const float lre = lre_[s], lim = lim_[s];

    // lookback: g = state at end of chunk c-1 (truncated geometric sum)
    float gre = 0.f, gim = 0.f;
    if (c > 0) {
        float are = lre, aim = lim;          // lam^32 (5 squarings)
#pragma unroll
        for (int t = 0; t < 5; ++t) {
            float nr = are * are - aim * aim, ni = 2.f * are * aim;
            are = nr; aim = ni;
        }
        const int depth = (c < 12) ? c : 12;
        float pwr = 1.f, pwi = 0.f;
        for (int j = c - 1; j >= c - depth; --j) {
            const size_t jb = (size_t)(b * NCH + j) * 512 + s;
            float er = carry[jb], ei = carry[jb + DS];
            gre = fmaf(pwr, er, fmaf(-pwi, ei, gre));
            gim = fmaf(pwr, ei, fmaf(pwi, er, gim));
            float nr = pwr * are - pwi * aim, ni = pwr * aim + pwi * are;
            pwr = nr; pwi = ni;
        }
    }

    // apply: rerun recurrence from g, write h
    float hr = gre, hi = gim;
    size_t base = ((size_t)b * SEQ + (size_t)c * LCH) * DS + s;
#pragma unroll 8
    for (int i = 0; i < LCH; ++i, base += DS) {
        uint_t uu = Bu[base];
        float br = bf2f(uu), bi = bf2f(uu >> 16);
        float nr = fmaf(lre, hr, fmaf(-lim, hi, br));
        float ni = fmaf(lre, hi, fmaf(lim, hr, bi));
        hr = nr; hi = ni;
        h[base] = pack2(hr, hi);
    }
}

// ---------------------------------------------------------------------------
extern "C" void kernel_launch(void* const* d_in, const int* in_sizes, int n_in,
                              void* d_out, int out_size, void* d_ws, size_t ws_size,
                              hipStream_t stream) {
    const float* u   = (const float*)d_in[0];
    const float* enc = (const float*)d_in[1];
    const float* dec = (const float*)d_in[2];
    const float* nu  = (const float*)d_in[3];
    const float* th  = (const float*)d_in[4];
    const float* Bre = (const float*)d_in[5];
    const float* Bim = (const float*)d_in[6];
    const float* Cre = (const float*)d_in[7];
    const float* Cim = (const float*)d_in[8];
    const float* Dp  = (const float*)d_in[9];
    const float* W1  = (const float*)d_in[10];
    const float* W2  = (const float*)d_in[11];
    const float* res = (const float*)d_in[12];
    float* out = (float*)d_out;

    const size_t MD = (size_t)MROWS * DM;
    float* carry = (float*)d_ws;                         // [8*64,512] fp32
    float* lre  = carry + (size_t)BATCH * NCH * 512;
    float* lim  = lre + NL * DS;
    float* gmt  = lim + NL * DS;
    ushort_t* xbf  = (ushort_t*)(gmt + NL * DS);         // bf16 [16384,512] each:
    ushort_t* Bubf = xbf + MD;
    ushort_t* hbf  = Bubf + MD;
    ushort_t* zbf  = hbf + MD;
    ushort_t* ubf  = zbf;                                // alias: z written after u consumed
    ushort_t* WBb  = zbf + MD;                           // weights, 4x512x512 bf16 each:
    ushort_t* Wzb  = WBb + (size_t)NL * DM * DM;
    ushort_t* W1b  = Wzb + (size_t)NL * DM * DM;
    ushort_t* W2b  = W1b + (size_t)NL * DM * DM;
    ushort_t* encb = W2b + (size_t)NL * DM * DM;         // 512x64
    ushort_t* decb = encb + DM * 64;                     // 64x512

    prep_all<<<NL * DM * DM / 256, 256, 0, stream>>>(
        u, enc, dec, nu, th, Bre, Bim, Cre, Cim, W1, W2,
        WBb, Wzb, W1b, W2b, encb, decb, ubf, lre, lim, gmt);

    const dim3 gFull(MROWS / 128, DM / 128);

    // encoder: xbf = bf16(u @ enc^T)
    {
        GemmArgs a = {};
        a.A = ubf; a.Wa = encb; a.K = 64; a.N = DM;
        a.obf = xbf;
        mgemm<128, 0, 0><<<gFull, 256, 0, stream>>>(a);
    }

    for (int k = 0; k < NL; ++k) {
        {   // Bu (interleaved re/im cols, gamma-scaled) -> Bubf, + fused chunk-ends
            GemmArgs a = {};
            a.A = xbf; a.Wa = WBb + (size_t)k * DM * DM; a.K = DM; a.N = DM;
            a.obf = Bubf; a.gam = gmt + k * DS;
            a.lamre = lre + k * DS; a.lamim = lim + k * DS; a.carry = carry;
            mgemm<128, 1, 0><<<gFull, 256, 0, stream>>>(a);
        }
        scan_apply_lb<<<BATCH * NCH, 256, 0, stream>>>((const uint_t*)Bubf,
                                                       lre + k * DS, lim + k * DS, carry,
                                                       (uint_t*)hbf);
        {   // z = Re(h @ C^T) + D*x  -> zbf
            GemmArgs a = {};
            a.A = hbf; a.Wa = Wzb + (size_t)k * DM * DM; a.K = DM; a.N = DM;
            a.obf = zbf; a.xbf_in = xbf; a.Dv = Dp + k * DM;
            mgemm<128, 2, 0><<<gFull, 256, 0, stream>>>(a);
        }
        {   // xbf += sig(res)*[(z@W1^T)*sigmoid(z@W2^T)]   (bf16 RMW)
            GemmArgs a = {};
            a.A = zbf; a.Wa = W1b + (size_t)k * DM * DM; a.Wb = W2b + (size_t)k * DM * DM;
            a.K = DM; a.N = DM;
            a.obf = xbf; a.xbf_in = xbf; a.resp = res; a.layer = k;
            mgemm<128, 3, 1><<<gFull, 256, 0, stream>>>(a);
        }
    }
    {   // decoder: out = x @ dec^T
        GemmArgs a = {};
        a.A = xbf; a.Wa = decb; a.K = DM; a.N = 64;
        a.of32 = out;
        mgemm<64, 4, 0><<<dim3(MROWS / 128, 1), 256, 0, stream>>>(a);
    }
}